// Round 1
// baseline (549.164 us; speedup 1.0000x reference)
//
#include <hip/hip_runtime.h>

namespace {
constexpr int NB = 256;   // batch
constexpr int NT = 64;    // time rows per batch
constexpr int NA = 32;    // action dim
constexpr int NH = 512;   // hidden
constexpr int TT = 16;    // t-tile rows
}

// One block per batch element b. 512 threads = 8 waves (2/SIMD).
// Phases: tau encode -> tau@W2t (once per b) -> per t-tile:
//   a_emb -> LDS ; h = a_emb@W2a + tauc ; swish -> LDS ; out = s@W3 + b3.
__global__ __launch_bounds__(512, 2)
void me_enc_fused(const float* __restrict__ actions,
                  const float* __restrict__ timesteps,
                  const int*   __restrict__ cat_ids,
                  const float* __restrict__ W1,
                  const float* __restrict__ b1,
                  const float* __restrict__ W2,
                  const float* __restrict__ b2,
                  const float* __restrict__ W3,
                  const float* __restrict__ b3,
                  float* __restrict__ out)
{
    __shared__ float tau_s[NH];
    __shared__ float tauc_s[NH];
    __shared__ float act_s[TT * NA];
    __shared__ float buf_s[TT][NH];   // a_emb, then swish output

    const int b   = blockIdx.x;
    const int tid = threadIdx.x;
    const int cat = cat_ids[b];
    const float t = timesteps[b];

    const float* __restrict__ W1c = W1 + (size_t)cat * NA * NH;
    const float* __restrict__ W2c = W2 + (size_t)cat * 2 * NH * NH;  // rows 0..H-1  (a_emb part)
    const float* __restrict__ W2t = W2c + (size_t)NH * NH;           // rows H..2H-1 (tau part)
    const float* __restrict__ W3c = W3 + (size_t)cat * NH * NH;

    // ---- P0: sinusoidal tau(t) — constant across T ----
    {
        const int k = tid;                       // exactly 512 threads
        const int i = k & 255;
        const float f   = __expf(-(float)i * 0.036118982f);  // ln(1e4)/255
        const float ang = t * f;
        tau_s[k] = (k < 256) ? __sinf(ang) : __cosf(ang);
    }
    __syncthreads();

    // ---- P1: tauc[h] = b2[h] + sum_k tau[k] * W2t[k][h]  (once per b) ----
    {
        float c0 = 0.f, c1 = 0.f, c2 = 0.f, c3 = 0.f;
        #pragma unroll 4
        for (int k = 0; k < NH; k += 4) {
            c0 += tau_s[k+0] * W2t[(size_t)(k+0)*NH + tid];
            c1 += tau_s[k+1] * W2t[(size_t)(k+1)*NH + tid];
            c2 += tau_s[k+2] * W2t[(size_t)(k+2)*NH + tid];
            c3 += tau_s[k+3] * W2t[(size_t)(k+3)*NH + tid];
        }
        tauc_s[tid] = b2[cat*NH + tid] + ((c0+c1)+(c2+c3));
    }

    const float b1v = b1[cat*NH + tid];
    const int j2   = tid & 255;       // column pair (j2, j2+256)
    const int grp  = tid >> 8;        // 0/1: which 8 t-rows this thread owns
    const int tl0  = grp * 8;
    const float b3v0 = b3[cat*NH + j2];
    const float b3v1 = b3[cat*NH + j2 + 256];
    const size_t obase = (size_t)b * NT * NH;

    float acc0[8], acc1[8];

    for (int t0 = 0; t0 < NT; t0 += TT) {
        // stage action tile (TT*NA = 512 elements, one per thread)
        act_s[tid] = actions[(size_t)b*NT*NA + (size_t)(t0 + (tid >> 5))*NA + (tid & 31)];
        __syncthreads();

        // ---- P2a: a_emb[tl][h] for h = tid ----
        {
            float acc[TT];
            #pragma unroll
            for (int l = 0; l < TT; ++l) acc[l] = b1v;
            #pragma unroll 4
            for (int a = 0; a < NA; ++a) {
                const float w = W1c[(size_t)a*NH + tid];
                #pragma unroll
                for (int l = 0; l < TT; ++l)
                    acc[l] += act_s[l*NA + a] * w;
            }
            #pragma unroll
            for (int l = 0; l < TT; ++l) buf_s[l][tid] = acc[l];
        }
        __syncthreads();

        // ---- P2b: h = a_emb @ W2a + tauc ----
        {
            const float tc0 = tauc_s[j2];
            const float tc1 = tauc_s[j2 + 256];
            #pragma unroll
            for (int l = 0; l < 8; ++l) { acc0[l] = tc0; acc1[l] = tc1; }
            #pragma unroll 4
            for (int k = 0; k < NH; k += 4) {
                const float* wp = W2c + (size_t)k*NH + j2;
                const float wa0 = wp[0],      wb0 = wp[256];
                const float wa1 = wp[NH],     wb1 = wp[NH + 256];
                const float wa2 = wp[2*NH],   wb2 = wp[2*NH + 256];
                const float wa3 = wp[3*NH],   wb3 = wp[3*NH + 256];
                #pragma unroll
                for (int l = 0; l < 8; ++l) {
                    const float4 av = *reinterpret_cast<const float4*>(&buf_s[tl0 + l][k]);
                    acc0[l] += av.x * wa0;  acc1[l] += av.x * wb0;
                    acc0[l] += av.y * wa1;  acc1[l] += av.y * wb1;
                    acc0[l] += av.z * wa2;  acc1[l] += av.z * wb2;
                    acc0[l] += av.w * wa3;  acc1[l] += av.w * wb3;
                }
            }
        }
        __syncthreads();   // all buf_s (a_emb) reads complete

        // swish, back into buf_s
        #pragma unroll
        for (int l = 0; l < 8; ++l) {
            const float h0 = acc0[l];
            const float h1 = acc1[l];
            buf_s[tl0 + l][j2]       = h0 / (1.f + __expf(-h0));
            buf_s[tl0 + l][j2 + 256] = h1 / (1.f + __expf(-h1));
        }
        __syncthreads();

        // ---- P3: out = swish @ W3 + b3 ----
        {
            #pragma unroll
            for (int l = 0; l < 8; ++l) { acc0[l] = b3v0; acc1[l] = b3v1; }
            #pragma unroll 4
            for (int k = 0; k < NH; k += 4) {
                const float* wp = W3c + (size_t)k*NH + j2;
                const float wa0 = wp[0],      wb0 = wp[256];
                const float wa1 = wp[NH],     wb1 = wp[NH + 256];
                const float wa2 = wp[2*NH],   wb2 = wp[2*NH + 256];
                const float wa3 = wp[3*NH],   wb3 = wp[3*NH + 256];
                #pragma unroll
                for (int l = 0; l < 8; ++l) {
                    const float4 av = *reinterpret_cast<const float4*>(&buf_s[tl0 + l][k]);
                    acc0[l] += av.x * wa0;  acc1[l] += av.x * wb0;
                    acc0[l] += av.y * wa1;  acc1[l] += av.y * wb1;
                    acc0[l] += av.z * wa2;  acc1[l] += av.z * wb2;
                    acc0[l] += av.w * wa3;  acc1[l] += av.w * wb3;
                }
            }
            #pragma unroll
            for (int l = 0; l < 8; ++l) {
                out[obase + (size_t)(t0 + tl0 + l)*NH + j2]       = acc0[l];
                out[obase + (size_t)(t0 + tl0 + l)*NH + j2 + 256] = acc1[l];
            }
        }
        __syncthreads();   // guard buf_s/act_s before next tile
    }
}

extern "C" void kernel_launch(void* const* d_in, const int* in_sizes, int n_in,
                              void* d_out, int out_size, void* d_ws, size_t ws_size,
                              hipStream_t stream)
{
    const float* actions   = (const float*)d_in[0];
    const float* timesteps = (const float*)d_in[1];
    const int*   cat_ids   = (const int*)  d_in[2];
    const float* W1 = (const float*)d_in[3];
    const float* b1 = (const float*)d_in[4];
    const float* W2 = (const float*)d_in[5];
    const float* b2 = (const float*)d_in[6];
    const float* W3 = (const float*)d_in[7];
    const float* b3 = (const float*)d_in[8];
    float* out = (float*)d_out;

    (void)in_sizes; (void)n_in; (void)out_size; (void)d_ws; (void)ws_size;

    me_enc_fused<<<NB, 512, 0, stream>>>(actions, timesteps, cat_ids,
                                         W1, b1, W2, b2, W3, b3, out);
}

// Round 2
// 94.056 us; speedup vs baseline: 5.8387x; 5.8387x over previous
//
#include <hip/hip_runtime.h>

typedef __attribute__((ext_vector_type(8))) short bf16x8;
typedef __attribute__((ext_vector_type(4))) float f32x4;

namespace {
constexpr int NB = 256, NT = 64, NA = 32, NH = 512, NE = 16;

// workspace layout (bytes)
constexpr size_t W1P_OFF  = 0;
constexpr size_t W1P_SZ   = (size_t)NE * 32 * 64 * 16;        // 524,288
constexpr size_t W2AP_OFF = W1P_OFF + W1P_SZ;
constexpr size_t WFR_SZ   = (size_t)NE * 16 * 32 * 64 * 16;   // 8,388,608
constexpr size_t W3P_OFF  = W2AP_OFF + WFR_SZ;
constexpr size_t W2TP_OFF = W3P_OFF + WFR_SZ;
constexpr size_t W2TP_SZ  = (size_t)NE * NH * NH * 2;         // 8,388,608
constexpr size_t WS_NEED  = W2TP_OFF + W2TP_SZ;               // ~24.5 MB
}

__device__ __forceinline__ unsigned f2bf(float x) {
    union { float f; unsigned u; } v; v.f = x;
    return (v.u + 0x7FFFu + ((v.u >> 16) & 1u)) >> 16;   // RNE, low 16 bits valid
}
__device__ __forceinline__ float bf2f(unsigned short u) {
    union { unsigned u; float f; } v; v.u = ((unsigned)u) << 16;
    return v.f;
}

// ---------------------------------------------------------------------------
// pack_weights: f32 -> bf16, MFMA-B-fragment swizzled (W1, W2a, W3) and
// row-major (W2 tau half). Fragment f (within cat) = ((ks*32)+nt)*64+lane,
// lane holds W[ks*32 + (lane>>4)*8 + j][nt*16 + (lane&15)], j=0..7.
// ---------------------------------------------------------------------------
__global__ void pack_weights(const float* __restrict__ W1,
                             const float* __restrict__ W2,
                             const float* __restrict__ W3,
                             unsigned char* __restrict__ ws)
{
    const int idx = blockIdx.x * 256 + threadIdx.x;
    constexpr int NFRAG  = NE * 16 * 32 * 64;   // 524288 (per big weight)
    constexpr int NFRAG1 = NE * 32 * 64;        // 32768
    constexpr int NW2T   = NE * NH * NH / 8;    // 524288

    if (idx < 2 * NFRAG) {
        const bool isW3 = (idx >= NFRAG);
        const int f    = isW3 ? (idx - NFRAG) : idx;
        const int lane = f & 63;
        const int nt   = (f >> 6) & 31;
        const int ks   = (f >> 11) & 15;
        const int cat  = f >> 15;
        const float* __restrict__ src = isW3 ? (W3 + (size_t)cat * NH * NH)
                                             : (W2 + (size_t)cat * 2 * NH * NH);
        const int k0 = ks * 32 + ((lane >> 4) << 3);
        const int n  = nt * 16 + (lane & 15);
        unsigned rr[4];
        #pragma unroll
        for (int p = 0; p < 4; ++p) {
            const unsigned lo = f2bf(src[(size_t)(k0 + 2*p    ) * NH + n]);
            const unsigned hi = f2bf(src[(size_t)(k0 + 2*p + 1) * NH + n]);
            rr[p] = lo | (hi << 16);
        }
        uint4 r; r.x = rr[0]; r.y = rr[1]; r.z = rr[2]; r.w = rr[3];
        ((uint4*)(ws + (isW3 ? W3P_OFF : W2AP_OFF)))[f] = r;
    } else if (idx < 2 * NFRAG + NFRAG1) {
        const int f    = idx - 2 * NFRAG;
        const int lane = f & 63;
        const int nt   = (f >> 6) & 31;
        const int cat  = f >> 11;
        const float* __restrict__ src = W1 + (size_t)cat * NA * NH;
        const int k0 = (lane >> 4) << 3;       // K = 32, single k-step
        const int n  = nt * 16 + (lane & 15);
        unsigned rr[4];
        #pragma unroll
        for (int p = 0; p < 4; ++p) {
            const unsigned lo = f2bf(src[(size_t)(k0 + 2*p    ) * NH + n]);
            const unsigned hi = f2bf(src[(size_t)(k0 + 2*p + 1) * NH + n]);
            rr[p] = lo | (hi << 16);
        }
        uint4 r; r.x = rr[0]; r.y = rr[1]; r.z = rr[2]; r.w = rr[3];
        ((uint4*)(ws + W1P_OFF))[f] = r;
    } else if (idx < 2 * NFRAG + NFRAG1 + NW2T) {
        const int p   = idx - (2 * NFRAG + NFRAG1);
        const int cat = p >> 15;
        const int rem = p & 32767;
        const int k   = rem >> 6;              // 0..511 (tau-half row)
        const int c0  = (rem & 63) << 3;       // col base, 8 contiguous
        const float* __restrict__ src =
            W2 + (size_t)cat * 2 * NH * NH + (size_t)(NH + k) * NH + c0;
        const float4 a = ((const float4*)src)[0];
        const float4 b = ((const float4*)src)[1];
        uint4 r;
        r.x = f2bf(a.x) | (f2bf(a.y) << 16);
        r.y = f2bf(a.z) | (f2bf(a.w) << 16);
        r.z = f2bf(b.x) | (f2bf(b.y) << 16);
        r.w = f2bf(b.z) | (f2bf(b.w) << 16);
        ((uint4*)(ws + W2TP_OFF))[p] = r;      // row-major [cat][k][c]
    }
}

// ---------------------------------------------------------------------------
// Fused MFMA kernel. One block per batch element. 8 waves, wave grid 2(m)x4(n),
// wave tile 32 rows x 128 cols. 16x16x32 bf16 MFMA, f32 accumulate.
// ---------------------------------------------------------------------------
__global__ __launch_bounds__(512, 2)
void me_enc_mfma(const float* __restrict__ actions,
                 const float* __restrict__ timesteps,
                 const int*   __restrict__ cat_ids,
                 const float* __restrict__ b1,
                 const float* __restrict__ b2,
                 const float* __restrict__ b3,
                 const unsigned char* __restrict__ ws,
                 float* __restrict__ out)
{
    constexpr int LDA = 520;                       // ushorts/row: pad kills bank conflicts
    __shared__ unsigned short A_lds[NT * LDA];     // 66,560 B (a_emb, then swish)
    __shared__ float tau_s[NH];
    __shared__ float tauc_s[NH];

    const int b    = blockIdx.x;
    const int tid  = threadIdx.x;
    const int lane = tid & 63;
    const int wid  = tid >> 6;
    const int wm   = wid >> 2;          // 0..1
    const int wn   = wid & 3;           // 0..3
    const int lr   = lane & 15;         // col-in-tile (B/D) / row-in-tile (A)
    const int lg   = lane >> 4;         // 0..3
    const int cat  = cat_ids[b];
    const float t  = timesteps[b];

    // ---- P0: sinusoidal tau(t) (constant across T) ----
    {
        const int i = tid & 255;
        const float f   = __expf(-(float)i * 0.036118981f);  // ln(1e4)/255
        const float ang = t * f;
        tau_s[tid] = (tid < 256) ? __sinf(ang) : __cosf(ang);
    }
    __syncthreads();

    // ---- P1: layer 1 -> A_lds (bf16 a_emb) ----
    {
        const uint4* __restrict__ w1p =
            (const uint4*)(ws + W1P_OFF) + (size_t)cat * 32 * 64;
        bf16x8 af[2];
        #pragma unroll
        for (int mt = 0; mt < 2; ++mt) {
            const int row = wm * 32 + mt * 16 + lr;
            const float* ap = actions + ((size_t)b * NT + row) * NA + lg * 8;
            const float4 a0 = ((const float4*)ap)[0];
            const float4 a1 = ((const float4*)ap)[1];
            bf16x8 v;
            v[0] = (short)f2bf(a0.x); v[1] = (short)f2bf(a0.y);
            v[2] = (short)f2bf(a0.z); v[3] = (short)f2bf(a0.w);
            v[4] = (short)f2bf(a1.x); v[5] = (short)f2bf(a1.y);
            v[6] = (short)f2bf(a1.z); v[7] = (short)f2bf(a1.w);
            af[mt] = v;
        }
        #pragma unroll
        for (int j = 0; j < 8; ++j) {
            union { uint4 u; bf16x8 s; } bw;
            bw.u = w1p[(size_t)(wn * 8 + j) * 64 + lane];
            const int col = wn * 128 + j * 16 + lr;
            const float bias = b1[cat * NH + col];
            f32x4 c0 = {bias, bias, bias, bias};
            f32x4 c1 = c0;
            c0 = __builtin_amdgcn_mfma_f32_16x16x32_bf16(af[0], bw.s, c0, 0, 0, 0);
            c1 = __builtin_amdgcn_mfma_f32_16x16x32_bf16(af[1], bw.s, c1, 0, 0, 0);
            #pragma unroll
            for (int r = 0; r < 4; ++r) {
                A_lds[(wm*32 +      lg*4 + r) * LDA + col] = (unsigned short)f2bf(c0[r]);
                A_lds[(wm*32 + 16 + lg*4 + r) * LDA + col] = (unsigned short)f2bf(c1[r]);
            }
        }
    }

    // ---- P0b: tauc = b2 + tau @ W2t  (interleaves with P1; same barrier) ----
    {
        const unsigned short* __restrict__ w2t =
            (const unsigned short*)(ws + W2TP_OFF) + (size_t)cat * NH * NH + tid;
        float s = 0.f;
        #pragma unroll 8
        for (int k = 0; k < NH; ++k)
            s += tau_s[k] * bf2f(w2t[(size_t)k * NH]);
        tauc_s[tid] = b2[cat * NH + tid] + s;
    }
    __syncthreads();

    f32x4 acc[2][8];

    // ---- P2: h = a_emb @ W2a + tauc ----
    {
        #pragma unroll
        for (int j = 0; j < 8; ++j) {
            const float tc = tauc_s[wn * 128 + j * 16 + lr];
            f32x4 v = {tc, tc, tc, tc};
            acc[0][j] = v; acc[1][j] = v;
        }
        const uint4* __restrict__ wp =
            (const uint4*)(ws + W2AP_OFF) + (size_t)cat * 16 * 32 * 64;
        #pragma unroll 2
        for (int ks = 0; ks < 16; ++ks) {
            bf16x8 af[2];
            #pragma unroll
            for (int mt = 0; mt < 2; ++mt) {
                const int row = wm * 32 + mt * 16 + lr;
                af[mt] = *(const bf16x8*)&A_lds[row * LDA + ks * 32 + lg * 8];
            }
            const uint4* wk = wp + ((size_t)ks * 32 + wn * 8) * 64 + lane;
            #pragma unroll
            for (int j = 0; j < 8; ++j) {
                union { uint4 u; bf16x8 s; } bw;
                bw.u = wk[(size_t)j * 64];
                acc[0][j] = __builtin_amdgcn_mfma_f32_16x16x32_bf16(af[0], bw.s, acc[0][j], 0, 0, 0);
                acc[1][j] = __builtin_amdgcn_mfma_f32_16x16x32_bf16(af[1], bw.s, acc[1][j], 0, 0, 0);
            }
        }
    }
    __syncthreads();   // all A_lds reads complete

    // ---- swish -> A_lds (bf16) ----
    #pragma unroll
    for (int mt = 0; mt < 2; ++mt)
        #pragma unroll
        for (int j = 0; j < 8; ++j)
            #pragma unroll
            for (int r = 0; r < 4; ++r) {
                const float h  = acc[mt][j][r];
                const float sw = h / (1.f + __expf(-h));
                A_lds[(wm*32 + mt*16 + lg*4 + r) * LDA + wn*128 + j*16 + lr] =
                    (unsigned short)f2bf(sw);
            }
    __syncthreads();

    // ---- P3: out = swish @ W3 + b3 ----
    {
        #pragma unroll
        for (int j = 0; j < 8; ++j) {
            const float bias = b3[cat * NH + wn * 128 + j * 16 + lr];
            f32x4 v = {bias, bias, bias, bias};
            acc[0][j] = v; acc[1][j] = v;
        }
        const uint4* __restrict__ wp =
            (const uint4*)(ws + W3P_OFF) + (size_t)cat * 16 * 32 * 64;
        #pragma unroll 2
        for (int ks = 0; ks < 16; ++ks) {
            bf16x8 af[2];
            #pragma unroll
            for (int mt = 0; mt < 2; ++mt) {
                const int row = wm * 32 + mt * 16 + lr;
                af[mt] = *(const bf16x8*)&A_lds[row * LDA + ks * 32 + lg * 8];
            }
            const uint4* wk = wp + ((size_t)ks * 32 + wn * 8) * 64 + lane;
            #pragma unroll
            for (int j = 0; j < 8; ++j) {
                union { uint4 u; bf16x8 s; } bw;
                bw.u = wk[(size_t)j * 64];
                acc[0][j] = __builtin_amdgcn_mfma_f32_16x16x32_bf16(af[0], bw.s, acc[0][j], 0, 0, 0);
                acc[1][j] = __builtin_amdgcn_mfma_f32_16x16x32_bf16(af[1], bw.s, acc[1][j], 0, 0, 0);
            }
        }
        #pragma unroll
        for (int mt = 0; mt < 2; ++mt)
            #pragma unroll
            for (int j = 0; j < 8; ++j)
                #pragma unroll
                for (int r = 0; r < 4; ++r)
                    out[((size_t)b * NT + wm*32 + mt*16 + lg*4 + r) * NH
                        + wn*128 + j*16 + lr] = acc[mt][j][r];
    }
}

// ---------------------------------------------------------------------------
// Fallback (R1 f32 kernel) if ws is too small for packed weights.
// ---------------------------------------------------------------------------
__global__ __launch_bounds__(512, 2)
void me_enc_fused(const float* __restrict__ actions,
                  const float* __restrict__ timesteps,
                  const int*   __restrict__ cat_ids,
                  const float* __restrict__ W1,
                  const float* __restrict__ b1,
                  const float* __restrict__ W2,
                  const float* __restrict__ b2,
                  const float* __restrict__ W3,
                  const float* __restrict__ b3,
                  float* __restrict__ out)
{
    __shared__ float tau_s[NH];
    __shared__ float tauc_s[NH];
    __shared__ float act_s[16 * NA];
    __shared__ float buf_s[16][NH];

    const int b   = blockIdx.x;
    const int tid = threadIdx.x;
    const int cat = cat_ids[b];
    const float t = timesteps[b];

    const float* __restrict__ W1c = W1 + (size_t)cat * NA * NH;
    const float* __restrict__ W2c = W2 + (size_t)cat * 2 * NH * NH;
    const float* __restrict__ W2t = W2c + (size_t)NH * NH;
    const float* __restrict__ W3c = W3 + (size_t)cat * NH * NH;

    {
        const int i = tid & 255;
        const float f   = __expf(-(float)i * 0.036118981f);
        const float ang = t * f;
        tau_s[tid] = (tid < 256) ? __sinf(ang) : __cosf(ang);
    }
    __syncthreads();
    {
        float c0 = 0.f;
        for (int k = 0; k < NH; ++k)
            c0 += tau_s[k] * W2t[(size_t)k * NH + tid];
        tauc_s[tid] = b2[cat * NH + tid] + c0;
    }
    const float b1v = b1[cat * NH + tid];
    const int j2  = tid & 255;
    const int tl0 = (tid >> 8) * 8;
    const float b3v0 = b3[cat * NH + j2];
    const float b3v1 = b3[cat * NH + j2 + 256];
    const size_t obase = (size_t)b * NT * NH;
    float acc0[8], acc1[8];

    for (int t0 = 0; t0 < NT; t0 += 16) {
        act_s[tid] = actions[(size_t)b*NT*NA + (size_t)(t0 + (tid >> 5))*NA + (tid & 31)];
        __syncthreads();
        {
            float a_[16];
            #pragma unroll
            for (int l = 0; l < 16; ++l) a_[l] = b1v;
            for (int a = 0; a < NA; ++a) {
                const float w = W1c[(size_t)a * NH + tid];
                #pragma unroll
                for (int l = 0; l < 16; ++l) a_[l] += act_s[l*NA + a] * w;
            }
            #pragma unroll
            for (int l = 0; l < 16; ++l) buf_s[l][tid] = a_[l];
        }
        __syncthreads();
        {
            const float tc0 = tauc_s[j2], tc1 = tauc_s[j2 + 256];
            #pragma unroll
            for (int l = 0; l < 8; ++l) { acc0[l] = tc0; acc1[l] = tc1; }
            for (int k = 0; k < NH; ++k) {
                const float wa = W2c[(size_t)k*NH + j2];
                const float wb = W2c[(size_t)k*NH + j2 + 256];
                #pragma unroll
                for (int l = 0; l < 8; ++l) {
                    const float av = buf_s[tl0 + l][k];
                    acc0[l] += av * wa; acc1[l] += av * wb;
                }
            }
        }
        __syncthreads();
        #pragma unroll
        for (int l = 0; l < 8; ++l) {
            buf_s[tl0 + l][j2]       = acc0[l] / (1.f + __expf(-acc0[l]));
            buf_s[tl0 + l][j2 + 256] = acc1[l] / (1.f + __expf(-acc1[l]));
        }
        __syncthreads();
        {
            #pragma unroll
            for (int l = 0; l < 8; ++l) { acc0[l] = b3v0; acc1[l] = b3v1; }
            for (int k = 0; k < NH; ++k) {
                const float wa = W3c[(size_t)k*NH + j2];
                const float wb = W3c[(size_t)k*NH + j2 + 256];
                #pragma unroll
                for (int l = 0; l < 8; ++l) {
                    const float av = buf_s[tl0 + l][k];
                    acc0[l] += av * wa; acc1[l] += av * wb;
                }
            }
            #pragma unroll
            for (int l = 0; l < 8; ++l) {
                out[obase + (size_t)(t0 + tl0 + l)*NH + j2]       = acc0[l];
                out[obase + (size_t)(t0 + tl0 + l)*NH + j2 + 256] = acc1[l];
            }
        }
        __syncthreads();
    }
}

extern "C" void kernel_launch(void* const* d_in, const int* in_sizes, int n_in,
                              void* d_out, int out_size, void* d_ws, size_t ws_size,
                              hipStream_t stream)
{
    const float* actions   = (const float*)d_in[0];
    const float* timesteps = (const float*)d_in[1];
    const int*   cat_ids   = (const int*)  d_in[2];
    const float* W1 = (const float*)d_in[3];
    const float* b1 = (const float*)d_in[4];
    const float* W2 = (const float*)d_in[5];
    const float* b2 = (const float*)d_in[6];
    const float* W3 = (const float*)d_in[7];
    const float* b3 = (const float*)d_in[8];
    float* out = (float*)d_out;

    (void)in_sizes; (void)n_in; (void)out_size;

    if (ws_size >= WS_NEED) {
        constexpr int PACK_THREADS = 2*NE*16*32*64 + NE*32*64 + NE*NH*NH/8;
        pack_weights<<<(PACK_THREADS + 255)/256, 256, 0, stream>>>(
            W1, W2, W3, (unsigned char*)d_ws);
        me_enc_mfma<<<NB, 512, 0, stream>>>(actions, timesteps, cat_ids,
                                            b1, b2, b3,
                                            (const unsigned char*)d_ws, out);
    } else {
        me_enc_fused<<<NB, 512, 0, stream>>>(actions, timesteps, cat_ids,
                                             W1, b1, W2, b2, W3, b3, out);
    }
}

// Round 3
// 68.265 us; speedup vs baseline: 8.0445x; 1.3778x over previous
//
#include <hip/hip_runtime.h>

typedef __attribute__((ext_vector_type(8))) short bf16x8;
typedef __attribute__((ext_vector_type(4))) float f32x4;

namespace {
constexpr int NB = 256, NT = 64, NA = 32, NH = 512, NE = 16;
constexpr int NK2 = 32;            // K-steps for layer 2 (K=1024)
constexpr int NK3 = 16;            // K-steps for layer 3 (K=512)
constexpr int LDA = 1032;          // A_lds row stride in ushorts (516 dw = 4 mod 32 -> 2-way = free)

// workspace layout (bytes)
constexpr size_t W1P_OFF = 0;
constexpr size_t W1P_SZ  = (size_t)NE * 32 * 64 * 16;          //    524,288
constexpr size_t W2P_OFF = W1P_OFF + W1P_SZ;
constexpr size_t W2P_SZ  = (size_t)NE * NK2 * 32 * 64 * 16;    // 16,777,216
constexpr size_t W3P_OFF = W2P_OFF + W2P_SZ;
constexpr size_t W3P_SZ  = (size_t)NE * NK3 * 32 * 64 * 16;    //  8,388,608
constexpr size_t PERM_OFF = W3P_OFF + W3P_SZ;
constexpr size_t WS_NEED  = PERM_OFF + (size_t)NB * 4;         // ~24.5 MiB
}

__device__ __forceinline__ unsigned f2bf(float x) {
    union { float f; unsigned u; } v; v.f = x;
    return (v.u + 0x7FFFu + ((v.u >> 16) & 1u)) >> 16;   // RNE, low 16 bits valid
}

// ---------------------------------------------------------------------------
// Deterministic cat-grouping: perm[rank] = b, rank = stable sort order by cat.
// ---------------------------------------------------------------------------
__global__ void sort_cats(const int* __restrict__ cat_ids, int* __restrict__ perm)
{
    __shared__ int cs[NB];
    const int b = threadIdx.x;
    cs[b] = cat_ids[b];
    __syncthreads();
    const int my = cs[b];
    int rank = 0;
    #pragma unroll 8
    for (int i = 0; i < NB; ++i) {
        const int c = cs[i];
        rank += (c < my) || (c == my && i < b);
    }
    perm[rank] = b;
}

// ---------------------------------------------------------------------------
// pack_weights: f32 -> bf16 MFMA-B fragments.
// Fragment layout per weight: [cat][ks][nt][lane], 16 B per (frag,lane):
// lane holds W[ks*32 + (lane>>4)*8 + j][nt*16 + (lane&15)], j = 0..7.
// ---------------------------------------------------------------------------
__global__ void pack_weights(const float* __restrict__ W1,
                             const float* __restrict__ W2,
                             const float* __restrict__ W3,
                             unsigned char* __restrict__ ws)
{
    const int idx = blockIdx.x * 256 + threadIdx.x;
    constexpr int NF2 = NE * NK2 * 32 * 64;   // 1,048,576
    constexpr int NF3 = NE * NK3 * 32 * 64;   //   524,288
    constexpr int NF1 = NE * 32 * 64;         //    32,768

    const float* src;
    uint4* dst;
    int fi, ks;
    if (idx < NF2) {
        fi = idx; ks = (fi >> 11) & 31;
        src = W2 + (size_t)(fi >> 16) * 1024 * NH;
        dst = (uint4*)(ws + W2P_OFF);
    } else if (idx < NF2 + NF3) {
        fi = idx - NF2; ks = (fi >> 11) & 15;
        src = W3 + (size_t)(fi >> 15) * NH * NH;
        dst = (uint4*)(ws + W3P_OFF);
    } else if (idx < NF2 + NF3 + NF1) {
        fi = idx - NF2 - NF3; ks = 0;
        src = W1 + (size_t)(fi >> 11) * NA * NH;
        dst = (uint4*)(ws + W1P_OFF);
    } else return;

    const int lane = fi & 63;
    const int nt   = (fi >> 6) & 31;
    const int k0   = ks * 32 + ((lane >> 4) << 3);
    const int n    = nt * 16 + (lane & 15);
    unsigned rr[4];
    #pragma unroll
    for (int p = 0; p < 4; ++p) {
        const unsigned lo = f2bf(src[(size_t)(k0 + 2*p    ) * NH + n]);
        const unsigned hi = f2bf(src[(size_t)(k0 + 2*p + 1) * NH + n]);
        rr[p] = lo | (hi << 16);
    }
    uint4 r; r.x = rr[0]; r.y = rr[1]; r.z = rr[2]; r.w = rr[3];
    dst[fi] = r;
}

// ---------------------------------------------------------------------------
// Pipelined GEMM tile: wave computes 32 rows x 64 cols, K = NKS*32.
// 3 rotating register buffers, B-fragments loaded 2-3 K-steps ahead.
// ---------------------------------------------------------------------------
template<int NKS>
__device__ __forceinline__ void gemm_pipe(const uint4* __restrict__ wptr,
                                          const unsigned short* __restrict__ A,
                                          const int aoff0, f32x4 acc[2][4])
{
    uint4 buf[3][4];
#define LOADG(bi, kk)                                                          \
    if ((kk) < NKS) {                                                          \
        _Pragma("unroll")                                                      \
        for (int j = 0; j < 4; ++j)                                            \
            buf[bi][j] = wptr[(size_t)(kk) * 2048 + j * 64];                   \
    }
#define STEPG(bi, kk)                                                          \
    if ((kk) < NKS) {                                                          \
        const bf16x8 af0 = *(const bf16x8*)&A[aoff0 + (kk) * 32];              \
        const bf16x8 af1 = *(const bf16x8*)&A[aoff0 + 16 * LDA + (kk) * 32];   \
        _Pragma("unroll")                                                      \
        for (int j = 0; j < 4; ++j) {                                          \
            union { uint4 u; bf16x8 s; } bw; bw.u = buf[bi][j];                \
            acc[0][j] = __builtin_amdgcn_mfma_f32_16x16x32_bf16(af0, bw.s, acc[0][j], 0, 0, 0); \
            acc[1][j] = __builtin_amdgcn_mfma_f32_16x16x32_bf16(af1, bw.s, acc[1][j], 0, 0, 0); \
        }                                                                      \
    }
    LOADG(0, 0); LOADG(1, 1);
    #pragma unroll
    for (int k = 0; k < NKS; k += 3) {
        LOADG(2, k + 2); STEPG(0, k);
        LOADG(0, k + 3); STEPG(1, k + 1);
        LOADG(1, k + 4); STEPG(2, k + 2);
    }
#undef LOADG
#undef STEPG
}

// ---------------------------------------------------------------------------
// Fused MFMA kernel. 1024 threads = 16 waves (2m x 8n), wave tile 32x64.
// Layer 2 is one K=1024 GEMM: A = [a_emb | replicated tau] in LDS.
// ---------------------------------------------------------------------------
__global__ __launch_bounds__(1024, 4)
void me_enc_mfma2(const float* __restrict__ actions,
                  const float* __restrict__ timesteps,
                  const int*   __restrict__ cat_ids,
                  const float* __restrict__ b1,
                  const float* __restrict__ b2,
                  const float* __restrict__ b3,
                  const unsigned char* __restrict__ ws,
                  float* __restrict__ out)
{
    __shared__ unsigned short A_lds[NT * LDA];   // 132,096 B
    __shared__ unsigned tau_u32[NH / 2];         // 1 KB

    const int bid  = blockIdx.x;
    const int tid  = threadIdx.x;
    const int lane = tid & 63;
    const int wid  = tid >> 6;          // 0..15
    const int wm   = wid >> 3;          // 0..1
    const int wn   = wid & 7;           // 0..7
    const int lr   = lane & 15;
    const int lg   = lane >> 4;

    const int* __restrict__ perm = (const int*)(ws + PERM_OFF);
    const int p   = ((bid & 7) << 5) | (bid >> 3);   // same-cat blocks -> same XCD
    const int b   = perm[p];
    const int cat = cat_ids[b];
    const float t = timesteps[b];

    // ---- P0: tau(t) -> bf16 pairs ----
    if (tid < 256) {
        const int i0 = (2 * tid) & 255, i1 = (2 * tid + 1) & 255;
        const float f0 = __expf(-(float)i0 * 0.036118981f);   // ln(1e4)/255
        const float f1 = __expf(-(float)i1 * 0.036118981f);
        float v0, v1;
        if (tid < 128) { v0 = __sinf(t * f0); v1 = __sinf(t * f1); }
        else           { v0 = __cosf(t * f0); v1 = __cosf(t * f1); }
        tau_u32[tid] = f2bf(v0) | (f2bf(v1) << 16);
    }
    __syncthreads();

    // ---- replicate tau into A_lds cols 512..1023 (all 64 rows) ----
    {
        unsigned* Ad = (unsigned*)A_lds;
        #pragma unroll
        for (int tI = 0; tI < 16; ++tI) {
            const int idx = tI * 1024 + tid;
            const int row = idx >> 8, dc = idx & 255;
            Ad[row * (LDA / 2) + 256 + dc] = tau_u32[dc];
        }
    }

    // ---- P1: layer 1 -> A_lds cols 0..511 (bf16 a_emb) ----
    {
        const uint4* __restrict__ w1p =
            (const uint4*)(ws + W1P_OFF) + (size_t)cat * 2048 + (size_t)(wn * 4) * 64 + lane;
        bf16x8 af[2];
        #pragma unroll
        for (int mt = 0; mt < 2; ++mt) {
            const int row = wm * 32 + mt * 16 + lr;
            const float* ap = actions + ((size_t)b * NT + row) * NA + lg * 8;
            const float4 a0 = ((const float4*)ap)[0];
            const float4 a1 = ((const float4*)ap)[1];
            bf16x8 v;
            v[0] = (short)f2bf(a0.x); v[1] = (short)f2bf(a0.y);
            v[2] = (short)f2bf(a0.z); v[3] = (short)f2bf(a0.w);
            v[4] = (short)f2bf(a1.x); v[5] = (short)f2bf(a1.y);
            v[6] = (short)f2bf(a1.z); v[7] = (short)f2bf(a1.w);
            af[mt] = v;
        }
        #pragma unroll
        for (int j = 0; j < 4; ++j) {
            union { uint4 u; bf16x8 s; } bw;
            bw.u = w1p[(size_t)j * 64];
            const int col  = wn * 64 + j * 16 + lr;
            const float bi = b1[cat * NH + col];
            f32x4 c0 = {bi, bi, bi, bi};
            f32x4 c1 = c0;
            c0 = __builtin_amdgcn_mfma_f32_16x16x32_bf16(af[0], bw.s, c0, 0, 0, 0);
            c1 = __builtin_amdgcn_mfma_f32_16x16x32_bf16(af[1], bw.s, c1, 0, 0, 0);
            #pragma unroll
            for (int r = 0; r < 4; ++r) {
                A_lds[(wm*32 +      lg*4 + r) * LDA + col] = (unsigned short)f2bf(c0[r]);
                A_lds[(wm*32 + 16 + lg*4 + r) * LDA + col] = (unsigned short)f2bf(c1[r]);
            }
        }
    }
    __syncthreads();

    const int aoff0 = (wm * 32 + lr) * LDA + lg * 8;
    f32x4 acc[2][4];

    // ---- P2: h = [a_emb | tau] @ W2 + b2   (K = 1024) ----
    #pragma unroll
    for (int j = 0; j < 4; ++j) {
        const float tc = b2[cat * NH + wn * 64 + j * 16 + lr];
        f32x4 v = {tc, tc, tc, tc};
        acc[0][j] = v; acc[1][j] = v;
    }
    gemm_pipe<NK2>((const uint4*)(ws + W2P_OFF) + (size_t)cat * NK2 * 2048 + (wn * 4) * 64 + lane,
                   A_lds, aoff0, acc);
    __syncthreads();   // all A_lds reads complete

    // ---- swish -> A_lds cols 0..511 ----
    #pragma unroll
    for (int mt = 0; mt < 2; ++mt)
        #pragma unroll
        for (int j = 0; j < 4; ++j)
            #pragma unroll
            for (int r = 0; r < 4; ++r) {
                const float h  = acc[mt][j][r];
                const float sw = h / (1.f + __expf(-h));
                A_lds[(wm*32 + mt*16 + lg*4 + r) * LDA + wn*64 + j*16 + lr] =
                    (unsigned short)f2bf(sw);
            }
    __syncthreads();

    // ---- P3: out = swish @ W3 + b3   (K = 512) ----
    #pragma unroll
    for (int j = 0; j < 4; ++j) {
        const float bi = b3[cat * NH + wn * 64 + j * 16 + lr];
        f32x4 v = {bi, bi, bi, bi};
        acc[0][j] = v; acc[1][j] = v;
    }
    gemm_pipe<NK3>((const uint4*)(ws + W3P_OFF) + (size_t)cat * NK3 * 2048 + (wn * 4) * 64 + lane,
                   A_lds, aoff0, acc);

    #pragma unroll
    for (int mt = 0; mt < 2; ++mt)
        #pragma unroll
        for (int j = 0; j < 4; ++j)
            #pragma unroll
            for (int r = 0; r < 4; ++r)
                out[((size_t)b * NT + wm*32 + mt*16 + lg*4 + r) * NH
                    + wn*64 + j*16 + lr] = acc[mt][j][r];
}

// ---------------------------------------------------------------------------
// Fallback (f32, no workspace) if ws is too small.
// ---------------------------------------------------------------------------
__global__ __launch_bounds__(512, 2)
void me_enc_fused(const float* __restrict__ actions,
                  const float* __restrict__ timesteps,
                  const int*   __restrict__ cat_ids,
                  const float* __restrict__ W1,
                  const float* __restrict__ b1,
                  const float* __restrict__ W2,
                  const float* __restrict__ b2,
                  const float* __restrict__ W3,
                  const float* __restrict__ b3,
                  float* __restrict__ out)
{
    __shared__ float tau_s[NH];
    __shared__ float tauc_s[NH];
    __shared__ float act_s[16 * NA];
    __shared__ float buf_s[16][NH];

    const int b   = blockIdx.x;
    const int tid = threadIdx.x;
    const int cat = cat_ids[b];
    const float t = timesteps[b];

    const float* __restrict__ W1c = W1 + (size_t)cat * NA * NH;
    const float* __restrict__ W2c = W2 + (size_t)cat * 2 * NH * NH;
    const float* __restrict__ W2t = W2c + (size_t)NH * NH;
    const float* __restrict__ W3c = W3 + (size_t)cat * NH * NH;

    {
        const int i = tid & 255;
        const float f   = __expf(-(float)i * 0.036118981f);
        const float ang = t * f;
        tau_s[tid] = (tid < 256) ? __sinf(ang) : __cosf(ang);
    }
    __syncthreads();
    {
        float c0 = 0.f;
        for (int k = 0; k < NH; ++k)
            c0 += tau_s[k] * W2t[(size_t)k * NH + tid];
        tauc_s[tid] = b2[cat * NH + tid] + c0;
    }
    const float b1v = b1[cat * NH + tid];
    const int j2  = tid & 255;
    const int tl0 = (tid >> 8) * 8;
    const float b3v0 = b3[cat * NH + j2];
    const float b3v1 = b3[cat * NH + j2 + 256];
    const size_t obase = (size_t)b * NT * NH;
    float acc0[8], acc1[8];

    for (int t0 = 0; t0 < NT; t0 += 16) {
        act_s[tid] = actions[(size_t)b*NT*NA + (size_t)(t0 + (tid >> 5))*NA + (tid & 31)];
        __syncthreads();
        {
            float a_[16];
            #pragma unroll
            for (int l = 0; l < 16; ++l) a_[l] = b1v;
            for (int a = 0; a < NA; ++a) {
                const float w = W1c[(size_t)a * NH + tid];
                #pragma unroll
                for (int l = 0; l < 16; ++l) a_[l] += act_s[l*NA + a] * w;
            }
            #pragma unroll
            for (int l = 0; l < 16; ++l) buf_s[l][tid] = a_[l];
        }
        __syncthreads();
        {
            const float tc0 = tauc_s[j2], tc1 = tauc_s[j2 + 256];
            #pragma unroll
            for (int l = 0; l < 8; ++l) { acc0[l] = tc0; acc1[l] = tc1; }
            for (int k = 0; k < NH; ++k) {
                const float wa = W2c[(size_t)k*NH + j2];
                const float wb = W2c[(size_t)k*NH + j2 + 256];
                #pragma unroll
                for (int l = 0; l < 8; ++l) {
                    const float av = buf_s[tl0 + l][k];
                    acc0[l] += av * wa; acc1[l] += av * wb;
                }
            }
        }
        __syncthreads();
        #pragma unroll
        for (int l = 0; l < 8; ++l) {
            buf_s[tl0 + l][j2]       = acc0[l] / (1.f + __expf(-acc0[l]));
            buf_s[tl0 + l][j2 + 256] = acc1[l] / (1.f + __expf(-acc1[l]));
        }
        __syncthreads();
        {
            #pragma unroll
            for (int l = 0; l < 8; ++l) { acc0[l] = b3v0; acc1[l] = b3v1; }
            for (int k = 0; k < NH; ++k) {
                const float wa = W3c[(size_t)k*NH + j2];
                const float wb = W3c[(size_t)k*NH + j2 + 256];
                #pragma unroll
                for (int l = 0; l < 8; ++l) {
                    const float av = buf_s[tl0 + l][k];
                    acc0[l] += av * wa; acc1[l] += av * wb;
                }
            }
            #pragma unroll
            for (int l = 0; l < 8; ++l) {
                out[obase + (size_t)(t0 + tl0 + l)*NH + j2]       = acc0[l];
                out[obase + (size_t)(t0 + tl0 + l)*NH + j2 + 256] = acc1[l];
            }
        }
        __syncthreads();
    }
}

extern "C" void kernel_launch(void* const* d_in, const int* in_sizes, int n_in,
                              void* d_out, int out_size, void* d_ws, size_t ws_size,
                              hipStream_t stream)
{
    const float* actions   = (const float*)d_in[0];
    const float* timesteps = (const float*)d_in[1];
    const int*   cat_ids   = (const int*)  d_in[2];
    const float* W1 = (const float*)d_in[3];
    const float* b1 = (const float*)d_in[4];
    const float* W2 = (const float*)d_in[5];
    const float* b2 = (const float*)d_in[6];
    const float* W3 = (const float*)d_in[7];
    const float* b3 = (const float*)d_in[8];
    float* out = (float*)d_out;

    (void)in_sizes; (void)n_in; (void)out_size;

    if (ws_size >= WS_NEED) {
        unsigned char* ws = (unsigned char*)d_ws;
        constexpr int PACK_THREADS = NE*NK2*32*64 + NE*NK3*32*64 + NE*32*64;
        pack_weights<<<(PACK_THREADS + 255)/256, 256, 0, stream>>>(W1, W2, W3, ws);
        sort_cats<<<1, NB, 0, stream>>>(cat_ids, (int*)(ws + PERM_OFF));
        me_enc_mfma2<<<NB, 1024, 0, stream>>>(actions, timesteps, cat_ids,
                                              b1, b2, b3, ws, out);
    } else {
        me_enc_fused<<<NB, 512, 0, stream>>>(actions, timesteps, cat_ids,
                                             W1, b1, W2, b2, W3, b3, out);
    }
}

// Round 4
// 59.150 us; speedup vs baseline: 9.2843x; 1.1541x over previous
//
#include <hip/hip_runtime.h>

typedef __attribute__((ext_vector_type(8))) short bf16x8;
typedef __attribute__((ext_vector_type(4))) float f32x4;

namespace {
constexpr int NB = 256, NT = 64, NA = 32, NH = 512, NE = 16;
constexpr int NK2 = 32;            // K-steps layer 2 (K=1024: 16 tau + 16 a_emb)
constexpr int NK3 = 16;            // K-steps layer 3 (K=512)
constexpr int LDAu = 520;          // A_lds row stride (ushorts)

// workspace layout (bytes)
constexpr size_t W1P_OFF = 0;
constexpr size_t W1P_SZ  = (size_t)NE * 32 * 64 * 16;          //    524,288
constexpr size_t W2P_OFF = W1P_OFF + W1P_SZ;
constexpr size_t W2P_SZ  = (size_t)NE * NK2 * 32 * 64 * 16;    // 16,777,216
constexpr size_t W3P_OFF = W2P_OFF + W2P_SZ;
constexpr size_t W3P_SZ  = (size_t)NE * NK3 * 32 * 64 * 16;    //  8,388,608
constexpr size_t PERM_OFF = W3P_OFF + W3P_SZ;
constexpr size_t WS_NEED  = PERM_OFF + (size_t)NB * 4;         // ~24.5 MiB
}

__device__ __forceinline__ unsigned f2bf(float x) {
    union { float f; unsigned u; } v; v.f = x;
    return (v.u + 0x7FFFu + ((v.u >> 16) & 1u)) >> 16;   // RNE, low 16 bits valid
}

// ---------------------------------------------------------------------------
// Deterministic cat-grouping: perm[rank] = b (stable sort by cat).
// ---------------------------------------------------------------------------
__global__ void sort_cats(const int* __restrict__ cat_ids, int* __restrict__ perm)
{
    __shared__ int cs[NB];
    const int b = threadIdx.x;
    cs[b] = cat_ids[b];
    __syncthreads();
    const int my = cs[b];
    int rank = 0;
    #pragma unroll 8
    for (int i = 0; i < NB; ++i) {
        const int c = cs[i];
        rank += (c < my) || (c == my && i < b);
    }
    perm[rank] = b;
}

// ---------------------------------------------------------------------------
// pack_weights: f32 -> bf16 MFMA-B fragments, [cat][ks][nt][lane] 16B each.
// Lane holds W[kbase + (lane>>4)*8 + j][nt*16 + (lane&15)], j=0..7.
// W2 k-step order: ks 0..15 = tau rows (512..1023), ks 16..31 = rows 0..511.
// ---------------------------------------------------------------------------
__global__ void pack_weights(const float* __restrict__ W1,
                             const float* __restrict__ W2,
                             const float* __restrict__ W3,
                             unsigned char* __restrict__ ws)
{
    const int idx = blockIdx.x * 256 + threadIdx.x;
    constexpr int NF2 = NE * NK2 * 32 * 64;   // 1,048,576
    constexpr int NF3 = NE * NK3 * 32 * 64;   //   524,288
    constexpr int NF1 = NE * 32 * 64;         //    32,768

    const float* src;
    uint4* dst;
    int fi, kbase;
    if (idx < NF2) {
        fi = idx;
        const int ks = (fi >> 11) & 31;
        kbase = (ks < 16) ? (512 + ks * 32) : ((ks - 16) * 32);
        src = W2 + (size_t)(fi >> 16) * 1024 * NH;
        dst = (uint4*)(ws + W2P_OFF);
    } else if (idx < NF2 + NF3) {
        fi = idx - NF2;
        kbase = ((fi >> 11) & 15) * 32;
        src = W3 + (size_t)(fi >> 15) * NH * NH;
        dst = (uint4*)(ws + W3P_OFF);
    } else if (idx < NF2 + NF3 + NF1) {
        fi = idx - NF2 - NF3;
        kbase = 0;
        src = W1 + (size_t)(fi >> 11) * NA * NH;
        dst = (uint4*)(ws + W1P_OFF);
    } else return;

    const int lane = fi & 63;
    const int nt   = (fi >> 6) & 31;
    const int k0   = kbase + ((lane >> 4) << 3);
    const int n    = nt * 16 + (lane & 15);
    unsigned rr[4];
    #pragma unroll
    for (int p = 0; p < 4; ++p) {
        const unsigned lo = f2bf(src[(size_t)(k0 + 2*p    ) * NH + n]);
        const unsigned hi = f2bf(src[(size_t)(k0 + 2*p + 1) * NH + n]);
        rr[p] = lo | (hi << 16);
    }
    uint4 r; r.x = rr[0]; r.y = rr[1]; r.z = rr[2]; r.w = rr[3];
    dst[fi] = r;
}

// ---------------------------------------------------------------------------
// Fused MFMA kernel. 1024 threads = 16 waves, wave grid 1x16: each wave owns
// all 64 rows x 32 cols -> every B-fragment loaded exactly once per block.
// ---------------------------------------------------------------------------
__global__ __launch_bounds__(1024, 4)
void me_enc_mfma3(const float* __restrict__ actions,
                  const float* __restrict__ timesteps,
                  const int*   __restrict__ cat_ids,
                  const float* __restrict__ b1,
                  const float* __restrict__ b2,
                  const float* __restrict__ b3,
                  const unsigned char* __restrict__ ws,
                  float* __restrict__ out)
{
    __shared__ unsigned short A_lds[NT * LDAu];   // 66,560 B
    __shared__ unsigned tau_u32[NH / 2];          //  1,024 B

    const int bid  = blockIdx.x;
    const int tid  = threadIdx.x;
    const int lane = tid & 63;
    const int wn   = tid >> 6;          // 0..15: 32-col slice
    const int lr   = lane & 15;
    const int lg   = lane >> 4;
    const int col0 = wn * 32;

    const int* __restrict__ perm = (const int*)(ws + PERM_OFF);
    const int p   = ((bid & 7) << 5) | (bid >> 3);   // same-cat blocks -> same XCD
    const int b   = perm[p];
    const int cat = cat_ids[b];
    const float t = timesteps[b];

    // ---- early global loads (W1 frags, actions, biases) ----
    const uint4* __restrict__ w1p =
        (const uint4*)(ws + W1P_OFF) + (size_t)cat * 2048 + (size_t)(wn * 2) * 64 + lane;
    const uint4 bw1_0 = w1p[0];
    const uint4 bw1_1 = w1p[64];

    bf16x8 aact[4];
    #pragma unroll
    for (int mt = 0; mt < 4; ++mt) {
        const float* ap = actions + ((size_t)b * NT + mt * 16 + lr) * NA + lg * 8;
        const float4 a0 = ((const float4*)ap)[0];
        const float4 a1 = ((const float4*)ap)[1];
        bf16x8 v;
        v[0] = (short)f2bf(a0.x); v[1] = (short)f2bf(a0.y);
        v[2] = (short)f2bf(a0.z); v[3] = (short)f2bf(a0.w);
        v[4] = (short)f2bf(a1.x); v[5] = (short)f2bf(a1.y);
        v[6] = (short)f2bf(a1.z); v[7] = (short)f2bf(a1.w);
        aact[mt] = v;
    }
    float bias1[2], bias2[2], bias3[2];
    #pragma unroll
    for (int j = 0; j < 2; ++j) {
        const int c = cat * NH + col0 + j * 16 + lr;
        bias1[j] = b1[c]; bias2[j] = b2[c]; bias3[j] = b3[c];
    }

    // ---- tau(t) -> bf16 pairs ----
    if (tid < 256) {
        const int i0 = (2 * tid) & 255, i1 = i0 + 1;
        const float f0 = __expf(-(float)i0 * 0.036118981f);   // ln(1e4)/255
        const float f1 = __expf(-(float)i1 * 0.036118981f);
        float v0, v1;
        if (tid < 128) { v0 = __sinf(t * f0); v1 = __sinf(t * f1); }
        else           { v0 = __cosf(t * f0); v1 = __cosf(t * f1); }
        tau_u32[tid] = f2bf(v0) | (f2bf(v1) << 16);
    }
    __syncthreads();   // tau visible (early loads consumed right below anyway)

    f32x4 acc[4][2];

    // ---- P1: layer 1 -> A_lds (bf16 a_emb) ----
    #pragma unroll
    for (int j = 0; j < 2; ++j) {
        const f32x4 v = {bias1[j], bias1[j], bias1[j], bias1[j]};
        #pragma unroll
        for (int mt = 0; mt < 4; ++mt) acc[mt][j] = v;
    }
    {
        union { uint4 u; bf16x8 s; } wu0, wu1;
        wu0.u = bw1_0; wu1.u = bw1_1;
        #pragma unroll
        for (int mt = 0; mt < 4; ++mt) {
            acc[mt][0] = __builtin_amdgcn_mfma_f32_16x16x32_bf16(aact[mt], wu0.s, acc[mt][0], 0, 0, 0);
            acc[mt][1] = __builtin_amdgcn_mfma_f32_16x16x32_bf16(aact[mt], wu1.s, acc[mt][1], 0, 0, 0);
        }
    }
    #pragma unroll
    for (int mt = 0; mt < 4; ++mt)
        #pragma unroll
        for (int j = 0; j < 2; ++j)
            #pragma unroll
            for (int r = 0; r < 4; ++r)
                A_lds[(mt*16 + lg*4 + r) * LDAu + col0 + j*16 + lr] =
                    (unsigned short)f2bf(acc[mt][j][r]);
    asm volatile("s_waitcnt lgkmcnt(0)" ::: "memory");   // own a_emb writes done
    __builtin_amdgcn_sched_barrier(0);

    // ---- P2: h = [tau | a_emb] @ W2 + b2  (K=1024, continuous B stream) ----
    const unsigned short* __restrict__ tau_us = (const unsigned short*)tau_u32;
    #pragma unroll
    for (int j = 0; j < 2; ++j) {
        const f32x4 v = {bias2[j], bias2[j], bias2[j], bias2[j]};
        #pragma unroll
        for (int mt = 0; mt < 4; ++mt) acc[mt][j] = v;
    }
    const uint4* __restrict__ wp2 =
        (const uint4*)(ws + W2P_OFF) + (size_t)cat * NK2 * 2048 + (size_t)(wn * 2) * 64 + lane;
    uint4 buf[3][2];

#define LOAD2(bi, kk)                                                           \
    if ((kk) < NK2) {                                                           \
        buf[bi][0] = wp2[(size_t)(kk) * 2048];                                  \
        buf[bi][1] = wp2[(size_t)(kk) * 2048 + 64];                             \
    }
#define STEPK(bi, kk, NKS, AEOFF, BARK)                                         \
    if ((kk) < (NKS)) {                                                         \
        if ((kk) == (BARK)) {                                                   \
            __builtin_amdgcn_sched_barrier(0);                                  \
            __builtin_amdgcn_s_barrier();                                       \
            __builtin_amdgcn_sched_barrier(0);                                  \
        }                                                                       \
        bf16x8 af0, af1, af2, af3;                                              \
        if ((kk) < (AEOFF)) {                                                   \
            af0 = *(const bf16x8*)&tau_us[(kk) * 32 + lg * 8];                  \
            af1 = af0; af2 = af0; af3 = af0;                                    \
        } else {                                                                \
            const int ko = ((kk) - (AEOFF)) * 32 + lg * 8;                      \
            af0 = *(const bf16x8*)&A_lds[(     lr) * LDAu + ko];                \
            af1 = *(const bf16x8*)&A_lds[(16 + lr) * LDAu + ko];                \
            af2 = *(const bf16x8*)&A_lds[(32 + lr) * LDAu + ko];                \
            af3 = *(const bf16x8*)&A_lds[(48 + lr) * LDAu + ko];                \
        }                                                                       \
        union { uint4 u; bf16x8 s; } wu0, wu1;                                  \
        wu0.u = buf[bi][0]; wu1.u = buf[bi][1];                                 \
        acc[0][0] = __builtin_amdgcn_mfma_f32_16x16x32_bf16(af0, wu0.s, acc[0][0], 0, 0, 0); \
        acc[1][0] = __builtin_amdgcn_mfma_f32_16x16x32_bf16(af1, wu0.s, acc[1][0], 0, 0, 0); \
        acc[2][0] = __builtin_amdgcn_mfma_f32_16x16x32_bf16(af2, wu0.s, acc[2][0], 0, 0, 0); \
        acc[3][0] = __builtin_amdgcn_mfma_f32_16x16x32_bf16(af3, wu0.s, acc[3][0], 0, 0, 0); \
        acc[0][1] = __builtin_amdgcn_mfma_f32_16x16x32_bf16(af0, wu1.s, acc[0][1], 0, 0, 0); \
        acc[1][1] = __builtin_amdgcn_mfma_f32_16x16x32_bf16(af1, wu1.s, acc[1][1], 0, 0, 0); \
        acc[2][1] = __builtin_amdgcn_mfma_f32_16x16x32_bf16(af2, wu1.s, acc[2][1], 0, 0, 0); \
        acc[3][1] = __builtin_amdgcn_mfma_f32_16x16x32_bf16(af3, wu1.s, acc[3][1], 0, 0, 0); \
    }

    LOAD2(0, 0); LOAD2(1, 1);
    #pragma unroll
    for (int k = 0; k < NK2; k += 3) {
        LOAD2(2, k + 2); STEPK(0, k,     NK2, 16, 16);
        LOAD2(0, k + 3); STEPK(1, k + 1, NK2, 16, 16);
        LOAD2(1, k + 4); STEPK(2, k + 2, NK2, 16, 16);
    }
#undef LOAD2

    // ---- P3 prologue B loads (in flight across the swish barriers) ----
    const uint4* __restrict__ wp3 =
        (const uint4*)(ws + W3P_OFF) + (size_t)cat * NK3 * 2048 + (size_t)(wn * 2) * 64 + lane;
#define LOAD3(bi, kk)                                                           \
    if ((kk) < NK3) {                                                           \
        buf[bi][0] = wp3[(size_t)(kk) * 2048];                                  \
        buf[bi][1] = wp3[(size_t)(kk) * 2048 + 64];                             \
    }
    LOAD3(0, 0); LOAD3(1, 1);

    asm volatile("s_waitcnt lgkmcnt(0)" ::: "memory");   // P2 LDS reads drained
    __builtin_amdgcn_sched_barrier(0);
    __builtin_amdgcn_s_barrier();                        // all waves done reading A_lds
    __builtin_amdgcn_sched_barrier(0);

    // ---- swish -> A_lds (bf16) ----
    #pragma unroll
    for (int mt = 0; mt < 4; ++mt)
        #pragma unroll
        for (int j = 0; j < 2; ++j)
            #pragma unroll
            for (int r = 0; r < 4; ++r) {
                const float h  = acc[mt][j][r];
                const float sw = h / (1.f + __expf(-h));
                A_lds[(mt*16 + lg*4 + r) * LDAu + col0 + j*16 + lr] =
                    (unsigned short)f2bf(sw);
            }
    #pragma unroll
    for (int j = 0; j < 2; ++j) {
        const f32x4 v = {bias3[j], bias3[j], bias3[j], bias3[j]};
        #pragma unroll
        for (int mt = 0; mt < 4; ++mt) acc[mt][j] = v;
    }
    asm volatile("s_waitcnt lgkmcnt(0)" ::: "memory");   // own swish writes done
    __builtin_amdgcn_sched_barrier(0);
    __builtin_amdgcn_s_barrier();                        // swish visible to all
    __builtin_amdgcn_sched_barrier(0);

    // ---- P3: out = swish @ W3 + b3  (K=512) ----
    #pragma unroll
    for (int k = 0; k < NK3; k += 3) {
        LOAD3(2, k + 2); STEPK(0, k,     NK3, 0, -1);
        LOAD3(0, k + 3); STEPK(1, k + 1, NK3, 0, -1);
        LOAD3(1, k + 4); STEPK(2, k + 2, NK3, 0, -1);
    }
#undef LOAD3
#undef STEPK

    #pragma unroll
    for (int mt = 0; mt < 4; ++mt)
        #pragma unroll
        for (int j = 0; j < 2; ++j)
            #pragma unroll
            for (int r = 0; r < 4; ++r)
                __builtin_nontemporal_store(acc[mt][j][r],
                    &out[((size_t)b * NT + mt*16 + lg*4 + r) * NH + col0 + j*16 + lr]);
}

// ---------------------------------------------------------------------------
// Fallback (f32, no workspace) if ws is too small.
// ---------------------------------------------------------------------------
__global__ __launch_bounds__(512, 2)
void me_enc_fused(const float* __restrict__ actions,
                  const float* __restrict__ timesteps,
                  const int*   __restrict__ cat_ids,
                  const float* __restrict__ W1,
                  const float* __restrict__ b1,
                  const float* __restrict__ W2,
                  const float* __restrict__ b2,
                  const float* __restrict__ W3,
                  const float* __restrict__ b3,
                  float* __restrict__ out)
{
    __shared__ float tau_s[NH];
    __shared__ float tauc_s[NH];
    __shared__ float act_s[16 * NA];
    __shared__ float buf_s[16][NH];

    const int b   = blockIdx.x;
    const int tid = threadIdx.x;
    const int cat = cat_ids[b];
    const float t = timesteps[b];

    const float* __restrict__ W1c = W1 + (size_t)cat * NA * NH;
    const float* __restrict__ W2c = W2 + (size_t)cat * 2 * NH * NH;
    const float* __restrict__ W2t = W2c + (size_t)NH * NH;
    const float* __restrict__ W3c = W3 + (size_t)cat * NH * NH;

    {
        const int i = tid & 255;
        const float f   = __expf(-(float)i * 0.036118981f);
        const float ang = t * f;
        tau_s[tid] = (tid < 256) ? __sinf(ang) : __cosf(ang);
    }
    __syncthreads();
    {
        float c0 = 0.f;
        for (int k = 0; k < NH; ++k)
            c0 += tau_s[k] * W2t[(size_t)k * NH + tid];
        tauc_s[tid] = b2[cat * NH + tid] + c0;
    }
    const float b1v = b1[cat * NH + tid];
    const int j2  = tid & 255;
    const int tl0 = (tid >> 8) * 8;
    const float b3v0 = b3[cat * NH + j2];
    const float b3v1 = b3[cat * NH + j2 + 256];
    const size_t obase = (size_t)b * NT * NH;
    float acc0[8], acc1[8];

    for (int t0 = 0; t0 < NT; t0 += 16) {
        act_s[tid] = actions[(size_t)b*NT*NA + (size_t)(t0 + (tid >> 5))*NA + (tid & 31)];
        __syncthreads();
        {
            float a_[16];
            #pragma unroll
            for (int l = 0; l < 16; ++l) a_[l] = b1v;
            for (int a = 0; a < NA; ++a) {
                const float w = W1c[(size_t)a * NH + tid];
                #pragma unroll
                for (int l = 0; l < 16; ++l) a_[l] += act_s[l*NA + a] * w;
            }
            #pragma unroll
            for (int l = 0; l < 16; ++l) buf_s[l][tid] = a_[l];
        }
        __syncthreads();
        {
            const float tc0 = tauc_s[j2], tc1 = tauc_s[j2 + 256];
            #pragma unroll
            for (int l = 0; l < 8; ++l) { acc0[l] = tc0; acc1[l] = tc1; }
            for (int k = 0; k < NH; ++k) {
                const float wa = W2c[(size_t)k*NH + j2];
                const float wb = W2c[(size_t)k*NH + j2 + 256];
                #pragma unroll
                for (int l = 0; l < 8; ++l) {
                    const float av = buf_s[tl0 + l][k];
                    acc0[l] += av * wa; acc1[l] += av * wb;
                }
            }
        }
        __syncthreads();
        #pragma unroll
        for (int l = 0; l < 8; ++l) {
            buf_s[tl0 + l][j2]       = acc0[l] / (1.f + __expf(-acc0[l]));
            buf_s[tl0 + l][j2 + 256] = acc1[l] / (1.f + __expf(-acc1[l]));
        }
        __syncthreads();
        {
            #pragma unroll
            for (int l = 0; l < 8; ++l) { acc0[l] = b3v0; acc1[l] = b3v1; }
            for (int k = 0; k < NH; ++k) {
                const float wa = W3c[(size_t)k*NH + j2];
                const float wb = W3c[(size_t)k*NH + j2 + 256];
                #pragma unroll
                for (int l = 0; l < 8; ++l) {
                    const float av = buf_s[tl0 + l][k];
                    acc0[l] += av * wa; acc1[l] += av * wb;
                }
            }
            #pragma unroll
            for (int l = 0; l < 8; ++l) {
                out[obase + (size_t)(t0 + tl0 + l)*NH + j2]       = acc0[l];
                out[obase + (size_t)(t0 + tl0 + l)*NH + j2 + 256] = acc1[l];
            }
        }
        __syncthreads();
    }
}

extern "C" void kernel_launch(void* const* d_in, const int* in_sizes, int n_in,
                              void* d_out, int out_size, void* d_ws, size_t ws_size,
                              hipStream_t stream)
{
    const float* actions   = (const float*)d_in[0];
    const float* timesteps = (const float*)d_in[1];
    const int*   cat_ids   = (const int*)  d_in[2];
    const float* W1 = (const float*)d_in[3];
    const float* b1 = (const float*)d_in[4];
    const float* W2 = (const float*)d_in[5];
    const float* b2 = (const float*)d_in[6];
    const float* W3 = (const float*)d_in[7];
    const float* b3 = (const float*)d_in[8];
    float* out = (float*)d_out;

    (void)in_sizes; (void)n_in; (void)out_size;

    if (ws_size >= WS_NEED) {
        unsigned char* ws = (unsigned char*)d_ws;
        sort_cats<<<1, NB, 0, stream>>>(cat_ids, (int*)(ws + PERM_OFF));
        constexpr int PACK_THREADS = NE*NK2*32*64 + NE*NK3*32*64 + NE*32*64;
        pack_weights<<<(PACK_THREADS + 255)/256, 256, 0, stream>>>(W1, W2, W3, ws);
        me_enc_mfma3<<<NB, 1024, 0, stream>>>(actions, timesteps, cat_ids,
                                              b1, b2, b3, ws, out);
    } else {
        me_enc_fused<<<NB, 512, 0, stream>>>(actions, timesteps, cat_ids,
                                             W1, b1, W2, b2, W3, b3, out);
    }
}

// Round 5
// 57.869 us; speedup vs baseline: 9.4898x; 1.0221x over previous
//
#include <hip/hip_runtime.h>

typedef __attribute__((ext_vector_type(8))) short bf16x8;
typedef __attribute__((ext_vector_type(4))) float f32x4;

namespace {
constexpr int NB = 256, NT = 64, NA = 32, NH = 512, NE = 16;
constexpr int NK2 = 32;            // K-steps layer 2 (K=1024: 16 tau + 16 a_emb)
constexpr int NK3 = 16;            // K-steps layer 3 (K=512)
constexpr int LDAu = 520;          // A_lds row stride (ushorts)
constexpr int MROW = 32;           // rows per block (half a batch element)

// workspace layout (bytes)
constexpr size_t W1P_OFF = 0;
constexpr size_t W1P_SZ  = (size_t)NE * 32 * 64 * 16;          //    524,288
constexpr size_t W2P_OFF = W1P_OFF + W1P_SZ;
constexpr size_t W2P_SZ  = (size_t)NE * NK2 * 32 * 64 * 16;    // 16,777,216
constexpr size_t W3P_OFF = W2P_OFF + W2P_SZ;
constexpr size_t W3P_SZ  = (size_t)NE * NK3 * 32 * 64 * 16;    //  8,388,608
constexpr size_t PERM_OFF = W3P_OFF + W3P_SZ;
constexpr size_t WS_NEED  = PERM_OFF + (size_t)NB * 4;         // ~24.5 MiB
}

__device__ __forceinline__ unsigned f2bf(float x) {
    union { float f; unsigned u; } v; v.f = x;
    return (v.u + 0x7FFFu + ((v.u >> 16) & 1u)) >> 16;   // RNE, low 16 bits valid
}

// ---------------------------------------------------------------------------
// pack_weights: f32 -> bf16 MFMA-B fragments, [cat][ks][nt][lane] 16B each.
// Lane holds W[kbase + (lane>>4)*8 + j][nt*16 + (lane&15)], j=0..7.
// W2 k-step order: ks 0..15 = tau rows (512..1023), ks 16..31 = rows 0..511.
// Block 0 additionally computes the cat-sorted permutation (saves a launch).
// ---------------------------------------------------------------------------
__global__ void pack_weights(const float* __restrict__ W1,
                             const float* __restrict__ W2,
                             const float* __restrict__ W3,
                             const int*   __restrict__ cat_ids,
                             unsigned char* __restrict__ ws)
{
    const int idx = blockIdx.x * 256 + threadIdx.x;
    constexpr int NF2 = NE * NK2 * 32 * 64;   // 1,048,576
    constexpr int NF3 = NE * NK3 * 32 * 64;   //   524,288
    constexpr int NF1 = NE * 32 * 64;         //    32,768

    const float* src = nullptr;
    uint4* dst = nullptr;
    int fi = 0, kbase = 0;
    bool have = true;
    if (idx < NF2) {
        fi = idx;
        const int ks = (fi >> 11) & 31;
        kbase = (ks < 16) ? (512 + ks * 32) : ((ks - 16) * 32);
        src = W2 + (size_t)(fi >> 16) * 1024 * NH;
        dst = (uint4*)(ws + W2P_OFF);
    } else if (idx < NF2 + NF3) {
        fi = idx - NF2;
        kbase = ((fi >> 11) & 15) * 32;
        src = W3 + (size_t)(fi >> 15) * NH * NH;
        dst = (uint4*)(ws + W3P_OFF);
    } else if (idx < NF2 + NF3 + NF1) {
        fi = idx - NF2 - NF3;
        kbase = 0;
        src = W1 + (size_t)(fi >> 11) * NA * NH;
        dst = (uint4*)(ws + W1P_OFF);
    } else have = false;

    if (have) {
        const int lane = fi & 63;
        const int nt   = (fi >> 6) & 31;
        const int k0   = kbase + ((lane >> 4) << 3);
        const int n    = nt * 16 + (lane & 15);
        unsigned rr[4];
        #pragma unroll
        for (int p = 0; p < 4; ++p) {
            const unsigned lo = f2bf(src[(size_t)(k0 + 2*p    ) * NH + n]);
            const unsigned hi = f2bf(src[(size_t)(k0 + 2*p + 1) * NH + n]);
            rr[p] = lo | (hi << 16);
        }
        uint4 r; r.x = rr[0]; r.y = rr[1]; r.z = rr[2]; r.w = rr[3];
        dst[fi] = r;
    }

    if (blockIdx.x == 0) {   // all 256 threads participate (uniform sync)
        __shared__ int cs[NB];
        const int bb = threadIdx.x;
        cs[bb] = cat_ids[bb];
        __syncthreads();
        const int my = cs[bb];
        int rank = 0;
        #pragma unroll 8
        for (int i = 0; i < NB; ++i) {
            const int c = cs[i];
            rank += (c < my) || (c == my && i < bb);
        }
        ((int*)(ws + PERM_OFF))[rank] = bb;
    }
}

// ---------------------------------------------------------------------------
// Fused MFMA kernel. Grid 512 = (batch, row-half): 2 blocks/CU.
// 512 threads = 8 waves, wave grid 1x8: wave owns 32 rows x 64 cols.
// Double-buffered A (A0 = a_emb, A1 = swish) -> only one mid-GEMM barrier
// (a_emb visibility, deferred behind the 16 tau k-steps) + one swish barrier.
// ---------------------------------------------------------------------------
__global__ __launch_bounds__(512, 4)
void me_enc_mfma4(const float* __restrict__ actions,
                  const float* __restrict__ timesteps,
                  const int*   __restrict__ cat_ids,
                  const float* __restrict__ b1,
                  const float* __restrict__ b2,
                  const float* __restrict__ b3,
                  const unsigned char* __restrict__ ws,
                  float* __restrict__ out)
{
    __shared__ unsigned short A0[MROW * LDAu];   // 33,280 B  (a_emb)
    __shared__ unsigned short A1[MROW * LDAu];   // 33,280 B  (swish)
    __shared__ unsigned tau_u32[NH / 2];         //  1,024 B

    const int bid  = blockIdx.x;
    const int tid  = threadIdx.x;
    const int lane = tid & 63;
    const int wn   = tid >> 6;          // 0..7: 64-col slice
    const int lr   = lane & 15;
    const int lg   = lane >> 4;
    const int col0 = wn * 64;

    // XCD-contiguous sorted order; halves of one b are adjacent (same XCD L2)
    const int sidx = ((bid & 7) << 6) | (bid >> 3);
    const int* __restrict__ perm = (const int*)(ws + PERM_OFF);
    const int b    = perm[sidx >> 1];
    const int half = sidx & 1;
    const int cat  = cat_ids[b];
    const float t  = timesteps[b];
    const int row0 = half * MROW;       // row offset within batch element

    // ---- early global loads (W1 frags, actions, biases) ----
    const uint4* __restrict__ w1p =
        (const uint4*)(ws + W1P_OFF) + (size_t)cat * 2048 + (size_t)(wn * 4) * 64 + lane;
    uint4 bw1[4];
    #pragma unroll
    for (int j = 0; j < 4; ++j) bw1[j] = w1p[(size_t)j * 64];

    bf16x8 aact[2];
    #pragma unroll
    for (int mt = 0; mt < 2; ++mt) {
        const float* ap = actions + ((size_t)b * NT + row0 + mt * 16 + lr) * NA + lg * 8;
        const float4 a0 = ((const float4*)ap)[0];
        const float4 a1 = ((const float4*)ap)[1];
        bf16x8 v;
        v[0] = (short)f2bf(a0.x); v[1] = (short)f2bf(a0.y);
        v[2] = (short)f2bf(a0.z); v[3] = (short)f2bf(a0.w);
        v[4] = (short)f2bf(a1.x); v[5] = (short)f2bf(a1.y);
        v[6] = (short)f2bf(a1.z); v[7] = (short)f2bf(a1.w);
        aact[mt] = v;
    }
    float bias1[4], bias2[4], bias3[4];
    #pragma unroll
    for (int j = 0; j < 4; ++j) {
        const int c = cat * NH + col0 + j * 16 + lr;
        bias1[j] = b1[c]; bias2[j] = b2[c]; bias3[j] = b3[c];
    }

    // ---- tau(t) -> bf16 pairs ----
    if (tid < 256) {
        const int i0 = (2 * tid) & 255, i1 = i0 + 1;
        const float f0 = __expf(-(float)i0 * 0.036118981f);   // ln(1e4)/255
        const float f1 = __expf(-(float)i1 * 0.036118981f);
        float v0, v1;
        if (tid < 128) { v0 = __sinf(t * f0); v1 = __sinf(t * f1); }
        else           { v0 = __cosf(t * f0); v1 = __cosf(t * f1); }
        tau_u32[tid] = f2bf(v0) | (f2bf(v1) << 16);
    }
    __syncthreads();   // tau visible

    f32x4 acc[2][4];

    // ---- P1: layer 1 -> A0 (bf16 a_emb, 32 rows x 512 cols) ----
    #pragma unroll
    for (int j = 0; j < 4; ++j) {
        const f32x4 v = {bias1[j], bias1[j], bias1[j], bias1[j]};
        acc[0][j] = v; acc[1][j] = v;
    }
    #pragma unroll
    for (int j = 0; j < 4; ++j) {
        union { uint4 u; bf16x8 v; } wu; wu.u = bw1[j];
        acc[0][j] = __builtin_amdgcn_mfma_f32_16x16x32_bf16(aact[0], wu.v, acc[0][j], 0, 0, 0);
        acc[1][j] = __builtin_amdgcn_mfma_f32_16x16x32_bf16(aact[1], wu.v, acc[1][j], 0, 0, 0);
    }
    #pragma unroll
    for (int mt = 0; mt < 2; ++mt)
        #pragma unroll
        for (int j = 0; j < 4; ++j)
            #pragma unroll
            for (int r = 0; r < 4; ++r)
                A0[(mt*16 + lg*4 + r) * LDAu + col0 + j*16 + lr] =
                    (unsigned short)f2bf(acc[mt][j][r]);
    asm volatile("s_waitcnt lgkmcnt(0)" ::: "memory");   // own a_emb writes in LDS
    __builtin_amdgcn_sched_barrier(0);

    // ---- P2: h = [tau | a_emb] @ W2 + b2  (K=1024, continuous B stream) ----
    const unsigned short* __restrict__ tau_us = (const unsigned short*)tau_u32;
    #pragma unroll
    for (int j = 0; j < 4; ++j) {
        const f32x4 v = {bias2[j], bias2[j], bias2[j], bias2[j]};
        acc[0][j] = v; acc[1][j] = v;
    }
    const uint4* __restrict__ wp2 =
        (const uint4*)(ws + W2P_OFF) + (size_t)cat * NK2 * 2048 + (size_t)(wn * 4) * 64 + lane;
    uint4 buf[3][4];

#define LOAD2(bi, kk)                                                           \
    if ((kk) < NK2) {                                                           \
        _Pragma("unroll")                                                       \
        for (int j = 0; j < 4; ++j)                                             \
            buf[bi][j] = wp2[(size_t)(kk) * 2048 + j * 64];                     \
    }
#define STEPK(bi, kk, NKS, AEOFF, BARK, ABUF)                                   \
    if ((kk) < (NKS)) {                                                         \
        if ((kk) == (BARK)) {                                                   \
            __builtin_amdgcn_sched_barrier(0);                                  \
            __builtin_amdgcn_s_barrier();                                       \
            __builtin_amdgcn_sched_barrier(0);                                  \
        }                                                                       \
        bf16x8 af0, af1;                                                        \
        if ((kk) < (AEOFF)) {                                                   \
            af0 = *(const bf16x8*)&tau_us[(kk) * 32 + lg * 8];                  \
            af1 = af0;                                                          \
        } else {                                                                \
            const int ko = ((kk) - (AEOFF)) * 32 + lg * 8;                      \
            af0 = *(const bf16x8*)&ABUF[(     lr) * LDAu + ko];                 \
            af1 = *(const bf16x8*)&ABUF[(16 + lr) * LDAu + ko];                 \
        }                                                                       \
        _Pragma("unroll")                                                       \
        for (int j = 0; j < 4; ++j) {                                           \
            union { uint4 u; bf16x8 v; } wu; wu.u = buf[bi][j];                 \
            acc[0][j] = __builtin_amdgcn_mfma_f32_16x16x32_bf16(af0, wu.v, acc[0][j], 0, 0, 0); \
            acc[1][j] = __builtin_amdgcn_mfma_f32_16x16x32_bf16(af1, wu.v, acc[1][j], 0, 0, 0); \
        }                                                                       \
    }

    LOAD2(0, 0); LOAD2(1, 1);
    #pragma unroll
    for (int k = 0; k < NK2; k += 3) {
        LOAD2(2, k + 2); STEPK(0, k,     NK2, 16, 16, A0);
        LOAD2(0, k + 3); STEPK(1, k + 1, NK2, 16, 16, A0);
        LOAD2(1, k + 4); STEPK(2, k + 2, NK2, 16, 16, A0);
    }
#undef LOAD2

    // ---- P3 prologue B loads (stay in flight across the swish barrier) ----
    const uint4* __restrict__ wp3 =
        (const uint4*)(ws + W3P_OFF) + (size_t)cat * NK3 * 2048 + (size_t)(wn * 4) * 64 + lane;
#define LOAD3(bi, kk)                                                           \
    if ((kk) < NK3) {                                                           \
        _Pragma("unroll")                                                       \
        for (int j = 0; j < 4; ++j)                                             \
            buf[bi][j] = wp3[(size_t)(kk) * 2048 + j * 64];                     \
    }
    LOAD3(0, 0); LOAD3(1, 1);

    // ---- swish -> A1 (no barrier needed before writes: A1 is fresh) ----
    #pragma unroll
    for (int mt = 0; mt < 2; ++mt)
        #pragma unroll
        for (int j = 0; j < 4; ++j)
            #pragma unroll
            for (int r = 0; r < 4; ++r) {
                const float h  = acc[mt][j][r];
                const float sw = h / (1.f + __expf(-h));
                A1[(mt*16 + lg*4 + r) * LDAu + col0 + j*16 + lr] =
                    (unsigned short)f2bf(sw);
            }
    #pragma unroll
    for (int j = 0; j < 4; ++j) {
        const f32x4 v = {bias3[j], bias3[j], bias3[j], bias3[j]};
        acc[0][j] = v; acc[1][j] = v;
    }
    asm volatile("s_waitcnt lgkmcnt(0)" ::: "memory");   // own swish writes in LDS
    __builtin_amdgcn_sched_barrier(0);
    __builtin_amdgcn_s_barrier();                        // swish visible to all
    __builtin_amdgcn_sched_barrier(0);

    // ---- P3: out = swish @ W3 + b3  (K=512) ----
    #pragma unroll
    for (int k = 0; k < NK3; k += 3) {
        LOAD3(2, k + 2); STEPK(0, k,     NK3, 0, -1, A1);
        LOAD3(0, k + 3); STEPK(1, k + 1, NK3, 0, -1, A1);
        LOAD3(1, k + 4); STEPK(2, k + 2, NK3, 0, -1, A1);
    }
#undef LOAD3
#undef STEPK

    #pragma unroll
    for (int mt = 0; mt < 2; ++mt)
        #pragma unroll
        for (int j = 0; j < 4; ++j)
            #pragma unroll
            for (int r = 0; r < 4; ++r)
                out[((size_t)b * NT + row0 + mt*16 + lg*4 + r) * NH
                    + col0 + j*16 + lr] = acc[mt][j][r];
}

// ---------------------------------------------------------------------------
// Fallback (f32, no workspace) if ws is too small.
// ---------------------------------------------------------------------------
__global__ __launch_bounds__(512, 2)
void me_enc_fused(const float* __restrict__ actions,
                  const float* __restrict__ timesteps,
                  const int*   __restrict__ cat_ids,
                  const float* __restrict__ W1,
                  const float* __restrict__ b1,
                  const float* __restrict__ W2,
                  const float* __restrict__ b2,
                  const float* __restrict__ W3,
                  const float* __restrict__ b3,
                  float* __restrict__ out)
{
    __shared__ float tau_s[NH];
    __shared__ float tauc_s[NH];
    __shared__ float act_s[16 * NA];
    __shared__ float buf_s[16][NH];

    const int b   = blockIdx.x;
    const int tid = threadIdx.x;
    const int cat = cat_ids[b];
    const float t = timesteps[b];

    const float* __restrict__ W1c = W1 + (size_t)cat * NA * NH;
    const float* __restrict__ W2c = W2 + (size_t)cat * 2 * NH * NH;
    const float* __restrict__ W2t = W2c + (size_t)NH * NH;
    const float* __restrict__ W3c = W3 + (size_t)cat * NH * NH;

    {
        const int i = tid & 255;
        const float f   = __expf(-(float)i * 0.036118981f);
        const float ang = t * f;
        tau_s[tid] = (tid < 256) ? __sinf(ang) : __cosf(ang);
    }
    __syncthreads();
    {
        float c0 = 0.f;
        for (int k = 0; k < NH; ++k)
            c0 += tau_s[k] * W2t[(size_t)k * NH + tid];
        tauc_s[tid] = b2[cat * NH + tid] + c0;
    }
    const float b1v = b1[cat * NH + tid];
    const int j2  = tid & 255;
    const int tl0 = (tid >> 8) * 8;
    const float b3v0 = b3[cat * NH + j2];
    const float b3v1 = b3[cat * NH + j2 + 256];
    const size_t obase = (size_t)b * NT * NH;
    float acc0[8], acc1[8];

    for (int t0 = 0; t0 < NT; t0 += 16) {
        act_s[tid] = actions[(size_t)b*NT*NA + (size_t)(t0 + (tid >> 5))*NA + (tid & 31)];
        __syncthreads();
        {
            float a_[16];
            #pragma unroll
            for (int l = 0; l < 16; ++l) a_[l] = b1v;
            for (int a = 0; a < NA; ++a) {
                const float w = W1c[(size_t)a * NH + tid];
                #pragma unroll
                for (int l = 0; l < 16; ++l) a_[l] += act_s[l*NA + a] * w;
            }
            #pragma unroll
            for (int l = 0; l < 16; ++l) buf_s[l][tid] = a_[l];
        }
        __syncthreads();
        {
            const float tc0 = tauc_s[j2], tc1 = tauc_s[j2 + 256];
            #pragma unroll
            for (int l = 0; l < 8; ++l) { acc0[l] = tc0; acc1[l] = tc1; }
            for (int k = 0; k < NH; ++k) {
                const float wa = W2c[(size_t)k*NH + j2];
                const float wb = W2c[(size_t)k*NH + j2 + 256];
                #pragma unroll
                for (int l = 0; l < 8; ++l) {
                    const float av = buf_s[tl0 + l][k];
                    acc0[l] += av * wa; acc1[l] += av * wb;
                }
            }
        }
        __syncthreads();
        #pragma unroll
        for (int l = 0; l < 8; ++l) {
            buf_s[tl0 + l][j2]       = acc0[l] / (1.f + __expf(-acc0[l]));
            buf_s[tl0 + l][j2 + 256] = acc1[l] / (1.f + __expf(-acc1[l]));
        }
        __syncthreads();
        {
            #pragma unroll
            for (int l = 0; l < 8; ++l) { acc0[l] = b3v0; acc1[l] = b3v1; }
            for (int k = 0; k < NH; ++k) {
                const float wa = W3c[(size_t)k*NH + j2];
                const float wb = W3c[(size_t)k*NH + j2 + 256];
                #pragma unroll
                for (int l = 0; l < 8; ++l) {
                    const float av = buf_s[tl0 + l][k];
                    acc0[l] += av * wa; acc1[l] += av * wb;
                }
            }
            #pragma unroll
            for (int l = 0; l < 8; ++l) {
                out[obase + (size_t)(t0 + tl0 + l)*NH + j2]       = acc0[l];
                out[obase + (size_t)(t0 + tl0 + l)*NH + j2 + 256] = acc1[l];
            }
        }
        __syncthreads();
    }
}

extern "C" void kernel_launch(void* const* d_in, const int* in_sizes, int n_in,
                              void* d_out, int out_size, void* d_ws, size_t ws_size,
                              hipStream_t stream)
{
    const float* actions   = (const float*)d_in[0];
    const float* timesteps = (const float*)d_in[1];
    const int*   cat_ids   = (const int*)  d_in[2];
    const float* W1 = (const float*)d_in[3];
    const float* b1 = (const float*)d_in[4];
    const float* W2 = (const float*)d_in[5];
    const float* b2 = (const float*)d_in[6];
    const float* W3 = (const float*)d_in[7];
    const float* b3 = (const float*)d_in[8];
    float* out = (float*)d_out;

    (void)in_sizes; (void)n_in; (void)out_size;

    if (ws_size >= WS_NEED) {
        unsigned char* ws = (unsigned char*)d_ws;
        constexpr int PACK_THREADS = NE*NK2*32*64 + NE*NK3*32*64 + NE*32*64;
        pack_weights<<<(PACK_THREADS + 255)/256, 256, 0, stream>>>(W1, W2, W3, cat_ids, ws);
        me_enc_mfma4<<<2 * NB, 512, 0, stream>>>(actions, timesteps, cat_ids,
                                                 b1, b2, b3, ws, out);
    } else {
        me_enc_fused<<<NB, 512, 0, stream>>>(actions, timesteps, cat_ids,
                                             W1, b1, W2, b2, W3, b3, out);
    }
}